// Round 1
// 355.811 us; speedup vs baseline: 1.1537x; 1.1537x over previous
//
#include <hip/hip_runtime.h>

// GcnEncoderGraph multi-kernel pipeline. B=8, N=2048, DIN=32, DH=DE=64, R=3.
// R8: (1) mask->bf16 expansion via 16-entry conflict-free LDS LUT (2x
// ds_read_b64 + ~7 VALU, was ~21 VALU) — gemm was VALU-bound on expansion;
// (2) combine rewritten: 2-barrier [rs][src][t][lane] redistribution, 4-wave
// parallel epilogue (was 7-barrier serial + 1-wave epilogue);
// (3) union bitplane precomputed in pack so gemm2/3 read 4 MiB not 12 MiB;
// (4) k_tail matvec reads concat row from LDS.
// 7 dispatches: pack+xw1, gemm1, xwh_bn, gemm2, xwh_bn, gemm3, tail.

#define NN 2048
#define PLANE_W 1048576L  // u32 words per bitplane: 8*2048*64

typedef short short8 __attribute__((ext_vector_type(8)));
typedef float floatx4 __attribute__((ext_vector_type(4)));

__device__ __forceinline__ unsigned short f2bf(float x) {
  unsigned u = __float_as_uint(x);
  u += 0x7FFFu + ((u >> 16) & 1u);
  return (unsigned short)(u >> 16);
}

// ---------- XW precompute (layer 1), swizzled to MFMA B-fragment order -------
__device__ void dev_xw_first(char* smemc, int u, int tid,
                             const float* __restrict__ x,
                             const float* __restrict__ w,
                             unsigned short* __restrict__ xws) {
  float* xs = (float*)smemc;                  // [64][33]
  float* wsh = (float*)(smemc + 64 * 33 * 4); // [32][64]
  const int jc = u & 31, b = (u >> 5) & 7, r = u >> 8;
  const int j0 = jc * 64;
  for (int idx = tid; idx < 64 * 32; idx += 256) {
    int row = idx >> 5, f = idx & 31;
    xs[row * 33 + f] = x[((long)b * NN + j0 + row) * 32 + f];
    wsh[idx] = w[r * 2048 + idx];  // [f][e]
  }
  __syncthreads();
  const int j = tid & 63, g = tid >> 6;
  const int k = j0 + j;
  const int kblk = k >> 5, kq = (k >> 3) & 3, kj = k & 7;
  unsigned short* dst =
      xws + (((long)(r * 8 + b) * 64 + kblk) * 4 + g) * 512 + kj;
  float xr[32];
#pragma unroll
  for (int f = 0; f < 32; ++f) xr[f] = xs[j * 33 + f];
#pragma unroll
  for (int ii = 0; ii < 16; ++ii) {
    float acc = 0.f;
#pragma unroll
    for (int f = 0; f < 32; ++f) acc += xr[f] * wsh[f * 64 + g * 16 + ii];
    dst[(kq * 16 + ii) * 8] = f2bf(acc);
  }
  __syncthreads();
}

// ---------- fused: pack relation -> 3 bitplanes + union, 768 blocks also xw1 -
__global__ __launch_bounds__(256) void k_pack_xw1(const int* __restrict__ rel,
                                                  unsigned* __restrict__ planes,
                                                  const float* __restrict__ x,
                                                  const float* __restrict__ w,
                                                  unsigned short* __restrict__ xws) {
  __shared__ __align__(16) char smem[16640];
  const int bid = blockIdx.x, tid = threadIdx.x;
  if (bid < 768) dev_xw_first(smem, bid, tid, x, w, xws);
  for (long t = (long)bid * 256 + tid; t < 1048576L; t += 4096L * 256) {
    int w32 = (int)(t & 63);
    long bi = t >> 6;  // b*2048 + i
    const int4* rp = (const int4*)(rel + bi * NN + w32 * 32);
    unsigned m0 = 0, m1 = 0, m2 = 0;
#pragma unroll
    for (int c = 0; c < 8; ++c) {
      int4 v = rp[c];
      int vv[4] = {v.x, v.y, v.z, v.w};
#pragma unroll
      for (int j = 0; j < 4; ++j) {
        unsigned b1 = 1u << (c * 4 + j);
        m0 |= (vv[j] == 1) ? b1 : 0u;
        m1 |= (vv[j] == 2) ? b1 : 0u;
        m2 |= (vv[j] == 3) ? b1 : 0u;
      }
    }
    long o = bi * 64 + w32;
    planes[o] = m0;
    planes[PLANE_W + o] = m1;
    planes[2 * PLANE_W + o] = m2;
    planes[3 * PLANE_W + o] = m0 | m1 | m2;  // union plane for gemm2/3
  }
}

// ---------- masked MFMA gemm: 8 waves interleave K, fused epilogue -----------
// grid 256: b = bid&7 (XCD affinity), it = bid>>3. Block 512 = 8 waves;
// wave w covers kblks == w (mod 8), all 64 rows (16 acc frags). Masks staged
// in 2 chunks of 32 kblks. Mask bits expand to bf16 A-fragments via a
// 16-entry LDS LUT (conflict-free: entry n -> banks {2n,2n+1}).
// Combine: 2-barrier [rs][src][t][lane] redistribution; wave w does the
// epilogue for rowset w (4-way parallel bias + L2norm + relu/pool).
template <int NREL, bool RELU, bool POOL3>
__global__ __launch_bounds__(512) void k_gemm8(
    const unsigned* __restrict__ planes, const unsigned short* __restrict__ xws,
    const float* __restrict__ bias, float* __restrict__ Hout,
    float* __restrict__ part3) {
  constexpr int MASK_BYTES = NREL * 8448;  // [NREL][64 rows][33 words]
  __shared__ __align__(16) char smem[65536];
  unsigned* mw = (unsigned*)smem;
  uint2* lut = (uint2*)(smem + MASK_BYTES);  // 16 x 8B nibble->2x bf16-pair
  floatx4* cb = (floatx4*)smem;              // 64 KB combine buffer (overlay)
  const int bid = blockIdx.x;
  const int b = bid & 7, it = bid >> 3;
  const int tid = threadIdx.x;
  const int wave = tid >> 6, lane = tid & 63;
  const int m = lane & 15, kq = lane >> 4;
  const unsigned shamt = kq * 8;
  const int i0 = it * 64;

  if (tid < 16) {
    unsigned n = tid;
    lut[n] = make_uint2(((n & 1u) ? 0x3f80u : 0u) | ((n & 2u) ? 0x3f800000u : 0u),
                        ((n & 4u) ? 0x3f80u : 0u) | ((n & 8u) ? 0x3f800000u : 0u));
  }

  floatx4 acc[4][4];  // [rowset][t]
#pragma unroll
  for (int rs = 0; rs < 4; ++rs)
#pragma unroll
    for (int t = 0; t < 4; ++t) acc[rs][t] = floatx4{0, 0, 0, 0};

  for (int chunk = 0; chunk < 2; ++chunk) {
    // stage 32 kblks of masks: coalesced 128B-per-row reads, stride-33 LDS
    for (int idx = tid; idx < NREL * 2048; idx += 512) {
      int p = idx >> 11, rem = idx & 2047, row = rem >> 5, w = rem & 31;
      long g = ((long)b * NN + i0 + row) * 64 + chunk * 32 + w;
      unsigned v;
      if (NREL == 3)
        v = planes[(long)p * PLANE_W + g];
      else
        v = planes[3 * PLANE_W + g];  // precomputed union plane
      mw[(p * 64 + row) * 33 + w] = v;
    }
    __syncthreads();
#pragma unroll
    for (int j = 0; j < 4; ++j) {
      const int kk = j * 8 + wave;           // chunk-local kblk
      const int kblk = chunk * 32 + kk;      // global kblk
#pragma unroll
      for (int p = 0; p < NREL; ++p) {
        const unsigned short* bb =
            xws + ((long)(p * 8 + b) * 64 + kblk) * 2048 + lane * 8;
        short8 bf0 = *(const short8*)(bb);
        short8 bf1 = *(const short8*)(bb + 512);
        short8 bf2 = *(const short8*)(bb + 1024);
        short8 bf3 = *(const short8*)(bb + 1536);
#pragma unroll
        for (int rs = 0; rs < 4; ++rs) {
          unsigned word = mw[(p * 64 + rs * 16 + m) * 33 + kk];
          unsigned byte = (word >> shamt) & 0xffu;
          uint2 lo = lut[byte & 15u];   // ds_read_b64, conflict-free
          uint2 hi = lut[byte >> 4];
          union {
            unsigned uu[4];
            short8 s8;
          } fr;
          fr.uu[0] = lo.x;  // {b0?1.0, b1?1.0} as packed bf16
          fr.uu[1] = lo.y;  // {b2, b3}
          fr.uu[2] = hi.x;  // {b4, b5}
          fr.uu[3] = hi.y;  // {b6, b7}
          acc[rs][0] = __builtin_amdgcn_mfma_f32_16x16x32_bf16(fr.s8, bf0,
                                                              acc[rs][0], 0, 0, 0);
          acc[rs][1] = __builtin_amdgcn_mfma_f32_16x16x32_bf16(fr.s8, bf1,
                                                              acc[rs][1], 0, 0, 0);
          acc[rs][2] = __builtin_amdgcn_mfma_f32_16x16x32_bf16(fr.s8, bf2,
                                                              acc[rs][2], 0, 0, 0);
          acc[rs][3] = __builtin_amdgcn_mfma_f32_16x16x32_bf16(fr.s8, bf3,
                                                              acc[rs][3], 0, 0, 0);
        }
      }
    }
    __syncthreads();
  }

  // --- combine: phase A — waves 4..7 write slots [rs][src][t][lane] ---
  if (wave >= 4) {
    const int src = wave - 4;
#pragma unroll
    for (int rs = 0; rs < 4; ++rs)
#pragma unroll
      for (int t = 0; t < 4; ++t)
        cb[((rs * 4 + src) * 4 + t) * 64 + lane] = acc[rs][t];
  }
  __syncthreads();
  // phase B — waves 0..3 fold their acc into their slot (exclusive RMW)
  if (wave < 4) {
#pragma unroll
    for (int rs = 0; rs < 4; ++rs)
#pragma unroll
      for (int t = 0; t < 4; ++t) {
        const int ix = ((rs * 4 + wave) * 4 + t) * 64 + lane;
        cb[ix] = cb[ix] + acc[rs][t];
      }
  }
  __syncthreads();
  // phase C — wave w sums 4 slots of rowset w, runs epilogue for its 16 rows
  if (wave < 4) {
    const int rs = wave;
    floatx4 s[4];
#pragma unroll
    for (int t = 0; t < 4; ++t) s[t] = cb[((rs * 4 + 0) * 4 + t) * 64 + lane];
#pragma unroll
    for (int src = 1; src < 4; ++src)
#pragma unroll
      for (int t = 0; t < 4; ++t)
        s[t] += cb[((rs * 4 + src) * 4 + t) * 64 + lane];
    float bv[4];
#pragma unroll
    for (int t = 0; t < 4; ++t) bv[t] = bias[t * 16 + m];
    float pmt[4] = {-3.4e38f, -3.4e38f, -3.4e38f, -3.4e38f};
#pragma unroll
    for (int reg = 0; reg < 4; ++reg) {
#pragma unroll
      for (int t = 0; t < 4; ++t) s[t][reg] += bv[t];
      float q = s[0][reg] * s[0][reg] + s[1][reg] * s[1][reg] +
                s[2][reg] * s[2][reg] + s[3][reg] * s[3][reg];
#pragma unroll
      for (int off = 1; off <= 8; off <<= 1) q += __shfl_xor(q, off);
      q = 1.0f / fmaxf(sqrtf(q), 1e-12f);
#pragma unroll
      for (int t = 0; t < 4; ++t) {
        float o = s[t][reg] * q;
        if (RELU) o = fmaxf(o, 0.0f);
        if (POOL3)
          pmt[t] = fmaxf(pmt[t], o);
        else
          Hout[((long)b * NN + i0 + rs * 16 + kq * 4 + reg) * 64 + t * 16 + m] = o;
      }
    }
    if (POOL3) {
#pragma unroll
      for (int t = 0; t < 4; ++t) {
        pmt[t] = fmaxf(pmt[t], __shfl_xor(pmt[t], 16));
        pmt[t] = fmaxf(pmt[t], __shfl_xor(pmt[t], 32));
      }
      // wave w finished reading its own 16KB quarter — reuse it for partials
      float* pm = (float*)(smem + wave * 16384);
      if (kq == 0) {
#pragma unroll
        for (int t = 0; t < 4; ++t) pm[t * 16 + m] = pmt[t];
      }
    }
  }
  if (POOL3) {
    __syncthreads();
    if (tid < 64) {
      float v = -3.4e38f;
#pragma unroll
      for (int w = 0; w < 4; ++w)
        v = fmaxf(v, ((const float*)(smem + w * 16384))[tid]);
      part3[((long)b * 32 + it) * 64 + tid] = v;
    }
  }
}

// ---------- fused BN + xw_h (+pool partial from b==0 blocks) -----------------
// block (jc = bid&31, b = bid>>5), 256 threads. BN stats per node over (bb,e)
// computed from H directly; HBN never materialized.
__global__ __launch_bounds__(256) void k_xwh_bn(const float* __restrict__ H,
                                                const float* __restrict__ w,
                                                unsigned short* __restrict__ xws,
                                                float* __restrict__ PP) {
  __shared__ float hs[64 * 65];
  __shared__ float wsh[64 * 64];
  __shared__ float sm[64], srs[64];
  const int bid = blockIdx.x, tid = threadIdx.x;
  const int jc = bid & 31, b = bid >> 5;
  const int j0 = jc * 64;
  // pass 1: stats. thread t: node n=t>>2, quarter q=t&3 (16 e each, all 8 bb)
  {
    const int n = tid >> 2, q = tid & 3;
    float s1 = 0.f, s2 = 0.f;
#pragma unroll
    for (int bb = 0; bb < 8; ++bb) {
      const float4* hp =
          (const float4*)(H + ((long)bb * NN + j0 + n) * 64 + q * 16);
#pragma unroll
      for (int c = 0; c < 4; ++c) {
        float4 v = hp[c];
        s1 += v.x + v.y + v.z + v.w;
        s2 += v.x * v.x + v.y * v.y + v.z * v.z + v.w * v.w;
      }
    }
    s1 += __shfl_xor(s1, 1);
    s2 += __shfl_xor(s2, 1);
    s1 += __shfl_xor(s1, 2);
    s2 += __shfl_xor(s2, 2);
    if (q == 0) {
      float mean = s1 * (1.0f / 512.0f);
      float var = fmaxf(s2 * (1.0f / 512.0f) - mean * mean, 0.0f);
      sm[n] = mean;
      srs[n] = rsqrtf(var + 1e-5f);
    }
  }
  __syncthreads();
  // pass 2: normalized tile for our b + weights
  for (int idx = tid; idx < 4096; idx += 256) {
    int row = idx >> 6, f = idx & 63;
    float v = H[((long)b * NN + j0 + row) * 64 + f];
    hs[row * 65 + f] = (v - sm[row]) * srs[row];
    wsh[idx] = w[idx];
  }
  __syncthreads();
  // pass 3: xw into swizzled fragment layout
  {
    const int j = tid & 63, g = tid >> 6;
    const int k = j0 + j;
    const int kblk = k >> 5, kq = (k >> 3) & 3, kj = k & 7;
    unsigned short* dst = xws + (((long)b * 64 + kblk) * 4 + g) * 512 + kj;
    float acc[16];
#pragma unroll
    for (int ii = 0; ii < 16; ++ii) acc[ii] = 0.f;
#pragma unroll
    for (int c = 0; c < 4; ++c) {
      float xr[16];
#pragma unroll
      for (int f = 0; f < 16; ++f) xr[f] = hs[j * 65 + c * 16 + f];
#pragma unroll
      for (int ii = 0; ii < 16; ++ii)
#pragma unroll
        for (int f = 0; f < 16; ++f)
          acc[ii] += xr[f] * wsh[(c * 16 + f) * 64 + g * 16 + ii];
    }
#pragma unroll
    for (int ii = 0; ii < 16; ++ii) dst[(kq * 16 + ii) * 8] = f2bf(acc[ii]);
  }
  // pass 4 (b==0 blocks): pool partials over our 64 nodes, all (bb,e)
  if (b == 0) {
#pragma unroll
    for (int part = 0; part < 2; ++part) {
      const int col = part * 256 + tid;
      const int bb = col >> 6, e = col & 63;
      float mx = -3.4e38f;
      for (int n = 0; n < 64; ++n) {
        float v = H[((long)bb * NN + j0 + n) * 64 + e];
        mx = fmaxf(mx, (v - sm[n]) * srs[n]);
      }
      PP[(long)jc * 512 + col] = mx;
    }
  }
}

// ---------- tail: all pool finals + linear head ------------------------------
__global__ __launch_bounds__(512) void k_tail(const float* __restrict__ PP1,
                                              const float* __restrict__ PP2,
                                              const float* __restrict__ P3,
                                              float* __restrict__ out,
                                              const float* __restrict__ wmap,
                                              const float* __restrict__ bmap) {
  __shared__ float obuf[8 * 192];
  const int col = threadIdx.x;
  const int bb = col >> 6, e = col & 63;
  float m1 = -3.4e38f, m2 = -3.4e38f, m3 = -3.4e38f;
#pragma unroll
  for (int c = 0; c < 32; ++c) {
    m1 = fmaxf(m1, PP1[(long)c * 512 + col]);
    m2 = fmaxf(m2, PP2[(long)c * 512 + col]);
    m3 = fmaxf(m3, P3[((long)bb * 32 + c) * 64 + e]);
  }
  out[bb * 192 + e] = m1;
  out[bb * 192 + 64 + e] = m2;
  out[bb * 192 + 128 + e] = m3;
  obuf[bb * 192 + e] = m1;
  obuf[bb * 192 + 64 + e] = m2;
  obuf[bb * 192 + 128 + e] = m3;
  __syncthreads();
  float acc = bmap[e];
#pragma unroll 4
  for (int k = 0; k < 192; ++k) acc += obuf[bb * 192 + k] * wmap[k * 64 + e];
  out[1536 + bb * 64 + e] = acc;
}

extern "C" void kernel_launch(void* const* d_in, const int* in_sizes, int n_in,
                              void* d_out, int out_size, void* d_ws,
                              size_t ws_size, hipStream_t stream) {
  const float* x = (const float*)d_in[0];
  const int* rel = (const int*)d_in[1];
  // d_in[2] (adj) unread: adj == (rel > 0) == union bitplane
  const float* w_first = (const float*)d_in[3];
  const float* b_first = (const float*)d_in[4];
  const float* w_block = (const float*)d_in[5];
  const float* b_block = (const float*)d_in[6];
  const float* w_last = (const float*)d_in[7];
  const float* b_last = (const float*)d_in[8];
  const float* w_map = (const float*)d_in[9];
  const float* b_map = (const float*)d_in[10];
  float* out = (float*)d_out;

  char* ws = (char*)d_ws;
  const size_t MB = 1024 * 1024;
  unsigned* PLANES = (unsigned*)(ws);                     // 16 MiB (4 planes)
  unsigned short* XWS = (unsigned short*)(ws + 16 * MB);  // 6 MiB
  float* H = (float*)(ws + 22 * MB);                      // 4 MiB
  float* PP1 = (float*)(ws + 26 * MB);                    // 64 KiB
  float* PP2 = (float*)(ws + 27 * MB);                    // 64 KiB
  float* PART3 = (float*)(ws + 28 * MB);                  // 64 KiB

  // ---- pack bitplanes (+union) + XW(layer1) ----
  k_pack_xw1<<<4096, 256, 0, stream>>>(rel, PLANES, x, w_first, XWS);
  // ---- layer 1 (fused bias+L2norm+relu) ----
  k_gemm8<3, true, false><<<256, 512, 0, stream>>>(PLANES, XWS, b_first, H,
                                                   nullptr);
  k_xwh_bn<<<256, 256, 0, stream>>>(H, w_block, XWS, PP1);
  // ---- layer 2 ----
  k_gemm8<1, true, false><<<256, 512, 0, stream>>>(PLANES, XWS, b_block, H,
                                                   nullptr);
  k_xwh_bn<<<256, 256, 0, stream>>>(H, w_last, XWS, PP2);
  // ---- layer 3 (fused L2norm + pool3 partial) ----
  k_gemm8<1, false, true><<<256, 512, 0, stream>>>(PLANES, XWS, b_last,
                                                   nullptr, PART3);
  // ---- pool finals + head ----
  k_tail<<<1, 512, 0, stream>>>(PP1, PP2, PART3, out, w_map, b_map);
}